// Round 5
// baseline (10861.756 us; speedup 1.0000x reference)
//
#include <hip/hip_runtime.h>
#include <hip/hip_bf16.h>

typedef unsigned int uint;
typedef unsigned short ushort;

typedef short s16x8 __attribute__((ext_vector_type(8)));
typedef float f32x4 __attribute__((ext_vector_type(4)));
typedef uint  u32x4 __attribute__((ext_vector_type(4)));

#define NB 8
#define NT 1024
#define NV 8192
#define ND 768
#define NH 12
#define NL 6
#define NDH 64
#define NFF 3072
#define NTOK (NB*NT)

__device__ __forceinline__ ushort f2bf(float f) {
  uint x = __float_as_uint(f);
  x += 0x7FFFu + ((x >> 16) & 1u);
  return (ushort)(x >> 16);
}
__device__ __forceinline__ float bf2f(ushort u) {
  return __uint_as_float(((uint)u) << 16);
}

// ---------------- embed ----------------
__global__ __launch_bounds__(192) void embed_kernel(
    const int* __restrict__ idx, const float* __restrict__ tok,
    const float* __restrict__ pos, float* __restrict__ x)
{
  int n = blockIdx.x, t = threadIdx.x;
  int token = idx[n];
  const float4* tp = (const float4*)(tok + (size_t)token * ND);
  const float4* pp = (const float4*)(pos + (size_t)(n & (NT - 1)) * ND);
  float4 a = tp[t], b = pp[t];
  float4 r; r.x = a.x + b.x; r.y = a.y + b.y; r.z = a.z + b.z; r.w = a.w + b.w;
  ((float4*)(x + (size_t)n * ND))[t] = r;
}

// ---------------- layernorm (f32 in -> bf16 out) ----------------
__global__ __launch_bounds__(256) void ln_kernel(
    const float* __restrict__ x, const float* __restrict__ g,
    const float* __restrict__ b, ushort* __restrict__ out)
{
  int row = blockIdx.x, tid = threadIdx.x;
  const float* xr = x + (size_t)row * ND;
  float v0 = xr[tid], v1 = xr[tid + 256], v2 = xr[tid + 512];
  float s = v0 + v1 + v2;
  float q = v0 * v0 + v1 * v1 + v2 * v2;
  #pragma unroll
  for (int d = 1; d < 64; d <<= 1) { s += __shfl_xor(s, d); q += __shfl_xor(q, d); }
  __shared__ float rs[4], rq[4];
  int w = tid >> 6;
  if ((tid & 63) == 0) { rs[w] = s; rq[w] = q; }
  __syncthreads();
  s = rs[0] + rs[1] + rs[2] + rs[3];
  q = rq[0] + rq[1] + rq[2] + rq[3];
  float mean = s * (1.0f / ND);
  float inv = rsqrtf(q * (1.0f / ND) - mean * mean + 1e-5f);
  ushort* orow = out + (size_t)row * ND;
  orow[tid]       = f2bf((v0 - mean) * inv * g[tid]       + b[tid]);
  orow[tid + 256] = f2bf((v1 - mean) * inv * g[tid + 256] + b[tid + 256]);
  orow[tid + 512] = f2bf((v2 - mean) * inv * g[tid + 512] + b[tid + 512]);
}

// ---------------- transpose + f32->bf16 convert ----------------
__global__ __launch_bounds__(256) void transp_conv(
    const float* __restrict__ in, ushort* __restrict__ out, int R, int C, int total)
{
  int o = blockIdx.x * 256 + threadIdx.x;
  if (o >= total) return;
  int rc = R * C;
  int bi = o / rc;
  int rem = o - bi * rc;
  int c = rem / R;
  int r = rem - c * R;
  out[o] = f2bf(in[(size_t)bi * rc + (size_t)r * C + c]);
}

// ---------------- bf16 MFMA GEMM: C[M,N] = A[M,K] @ Bt[N,K]^T ----------------
// OUT: 0 = none, 1 = bf16, 2 = f32
template<bool BIAS, bool RELU, bool RESID, int OUT>
__global__ __launch_bounds__(256) void gemm_bt(
    const ushort* __restrict__ A, const ushort* __restrict__ Bt,
    const float* __restrict__ bias, float* __restrict__ xres,
    void* __restrict__ outp, int M, int N, int K)
{
  __shared__ ushort As[128][48];
  __shared__ ushort Bs[128][48];
  const int tid = threadIdx.x;
  const int lane = tid & 63;
  const int w = tid >> 6;
  const int wr = w >> 1, wc = w & 1;
  const int lg = lane >> 4, li = lane & 15;
  const int m0 = blockIdx.y * 128, n0 = blockIdx.x * 128;
  const int sr = tid >> 2, sc = (tid & 3) * 8;

  f32x4 acc[4][4];
  #pragma unroll
  for (int i = 0; i < 4; ++i)
    #pragma unroll
    for (int j = 0; j < 4; ++j) { f32x4 z = {0.f,0.f,0.f,0.f}; acc[i][j] = z; }

  for (int kk = 0; kk < K; kk += 32) {
    __syncthreads();
    #pragma unroll
    for (int p = 0; p < 2; ++p) {
      int r = p * 64 + sr;
      *(u32x4*)&As[r][sc] = *(const u32x4*)&A[(size_t)(m0 + r) * K + kk + sc];
      *(u32x4*)&Bs[r][sc] = *(const u32x4*)&Bt[(size_t)(n0 + r) * K + kk + sc];
    }
    __syncthreads();
    s16x8 af[4], bfr[4];
    #pragma unroll
    for (int i = 0; i < 4; ++i) {
      af[i]  = *(const s16x8*)&As[wr * 64 + i * 16 + li][lg * 8];
      bfr[i] = *(const s16x8*)&Bs[wc * 64 + i * 16 + li][lg * 8];
    }
    #pragma unroll
    for (int i = 0; i < 4; ++i)
      #pragma unroll
      for (int j = 0; j < 4; ++j)
        acc[i][j] = __builtin_amdgcn_mfma_f32_16x16x32_bf16(af[i], bfr[j], acc[i][j], 0, 0, 0);
  }

  #pragma unroll
  for (int i = 0; i < 4; ++i) {
    #pragma unroll
    for (int j = 0; j < 4; ++j) {
      int row0 = m0 + wr * 64 + i * 16 + lg * 4;
      int col  = n0 + wc * 64 + j * 16 + li;
      float bv = BIAS ? bias[col] : 0.f;
      #pragma unroll
      for (int ii = 0; ii < 4; ++ii) {
        float val = acc[i][j][ii] + bv;
        if (RELU) val = fmaxf(val, 0.f);
        size_t off = (size_t)(row0 + ii) * N + col;
        if (RESID) { val += xres[off]; xres[off] = val; }
        if (OUT == 1) ((ushort*)outp)[off] = f2bf(val);
        if (OUT == 2) ((float*)outp)[off] = val;
      }
    }
  }
}

// ---------------- naive causal attention (proven ≡ MFMA variant) ----------
__global__ __launch_bounds__(256) void attn_naive(
    const ushort* __restrict__ q, const ushort* __restrict__ k,
    const ushort* __restrict__ v, ushort* __restrict__ o)
{
  __shared__ float qs[4][64];
  __shared__ float pw[4][64];
  const int tid = threadIdx.x;
  const int lane = tid & 63;
  const int w = tid >> 6;
  const int bid = blockIdx.x;
  const int qb4 = bid & 255;
  const int h = (bid >> 8) % NH;
  const int b = bid / (256 * NH);
  const int r = qb4 * 4 + w;
  const size_t nbase = (size_t)b * NT;
  const size_t hoff = (size_t)h * NDH;

  qs[w][lane] = bf2f(q[(nbase + r) * ND + hoff + lane]);

  float m = -1e30f, l = 0.f, acc = 0.f;
  const float scale = 0.036084391824351615f;  // 768^-0.5 (reference uses D, not DH)
  const int nkc = (r >> 6) + 1;
  for (int kc = 0; kc < nkc; ++kc) {
    int key = kc * 64 + lane;
    float s = 0.f;
    const ushort* kr = &k[(nbase + (size_t)(kc * 64 + lane)) * ND + hoff];
    #pragma unroll
    for (int j = 0; j < 8; ++j) {
      s16x8 kv = *(const s16x8*)&kr[j * 8];
      #pragma unroll
      for (int jj = 0; jj < 8; ++jj) s += qs[w][j * 8 + jj] * bf2f((ushort)kv[jj]);
    }
    s *= scale;
    if (key > r) s = -1e30f;
    float mx = s;
    #pragma unroll
    for (int d = 1; d < 64; d <<= 1) mx = fmaxf(mx, __shfl_xor(mx, d));
    float mnew = fmaxf(m, mx);
    float corr = __expf(m - mnew);
    float p = __expf(s - mnew);
    float ps = p;
    #pragma unroll
    for (int d = 1; d < 64; d <<= 1) ps += __shfl_xor(ps, d);
    l = l * corr + ps;
    m = mnew;
    pw[w][lane] = p;
    acc *= corr;
    int kmax = ((r >> 6) == kc) ? (r & 63) : 63;
    const ushort* vbase = &v[(nbase + (size_t)(kc * 64)) * ND + hoff + lane];
    for (int key2 = 0; key2 <= kmax; ++key2) {
      acc += pw[w][key2] * bf2f(vbase[(size_t)key2 * ND]);
    }
  }
  o[(nbase + r) * ND + hoff + lane] = f2bf(acc / l);
}

// ---------------- loss (f32 logits), deterministic two-stage ----------------
__global__ __launch_bounds__(256) void loss_row(
    const float* __restrict__ logits, const int* __restrict__ targets,
    float* __restrict__ rowloss)
{
  int row = blockIdx.x, tid = threadIdx.x;
  const float* lr = logits + (size_t)row * NV;
  const float4* l4 = (const float4*)lr;
  float vals[32];
  float mx = -1e30f;
  #pragma unroll
  for (int p = 0; p < 8; ++p) {
    float4 t = l4[p * 256 + tid];
    vals[p*4+0] = t.x; vals[p*4+1] = t.y; vals[p*4+2] = t.z; vals[p*4+3] = t.w;
    mx = fmaxf(mx, fmaxf(fmaxf(t.x, t.y), fmaxf(t.z, t.w)));
  }
  #pragma unroll
  for (int d = 1; d < 64; d <<= 1) mx = fmaxf(mx, __shfl_xor(mx, d));
  __shared__ float red[4], red2[4];
  int w = tid >> 6, lane = tid & 63;
  if (lane == 0) red[w] = mx;
  __syncthreads();
  mx = fmaxf(fmaxf(red[0], red[1]), fmaxf(red[2], red[3]));
  float sm = 0.f;
  #pragma unroll
  for (int i = 0; i < 32; ++i) sm += __expf(vals[i] - mx);
  #pragma unroll
  for (int d = 1; d < 64; d <<= 1) sm += __shfl_xor(sm, d);
  if (lane == 0) red2[w] = sm;
  __syncthreads();
  if (tid == 0) {
    float total = red2[0] + red2[1] + red2[2] + red2[3];
    float lse = mx + __logf(total);
    rowloss[row] = lse - lr[targets[row]];
  }
}

__global__ __launch_bounds__(256) void loss_reduce(
    const float* __restrict__ rowloss, float* __restrict__ out_loss)
{
  int tid = threadIdx.x;
  float s = 0.f;
  #pragma unroll
  for (int i = 0; i < 32; ++i) s += rowloss[tid + i * 256];
  #pragma unroll
  for (int d = 1; d < 64; d <<= 1) s += __shfl_xor(s, d);
  __shared__ float red[4];
  int w = tid >> 6, lane = tid & 63;
  if (lane == 0) red[w] = s;
  __syncthreads();
  if (tid == 0) {
    float total = red[0] + red[1] + red[2] + red[3];
    out_loss[0] = total * (1.0f / NTOK);
  }
}

// ---------------- launch ----------------
extern "C" void kernel_launch(void* const* d_in, const int* in_sizes, int n_in,
                              void* d_out, int out_size, void* d_ws, size_t ws_size,
                              hipStream_t stream)
{
  const int*   idx     = (const int*)d_in[0];
  const int*   targets = (const int*)d_in[1];
  const float* tok     = (const float*)d_in[2];
  const float* pos     = (const float*)d_in[3];
  const float* ln1g    = (const float*)d_in[4];
  const float* ln1b    = (const float*)d_in[5];
  const float* Wq      = (const float*)d_in[6];
  const float* Wk      = (const float*)d_in[7];
  const float* Wv      = (const float*)d_in[8];
  const float* Wp      = (const float*)d_in[9];
  const float* bp      = (const float*)d_in[10];
  const float* ln2g    = (const float*)d_in[11];
  const float* ln2b    = (const float*)d_in[12];
  const float* W1      = (const float*)d_in[13];
  const float* b1      = (const float*)d_in[14];
  const float* W2      = (const float*)d_in[15];
  const float* b2      = (const float*)d_in[16];
  const float* lnfg    = (const float*)d_in[17];
  const float* lnfb    = (const float*)d_in[18];
  const float* Wlm     = (const float*)d_in[19];
  const float* blm     = (const float*)d_in[20];

  // d_out is FLOAT32: out_size = NTOK*NV + 1 elements = 268,435,460 bytes.
  // Scratch phase uses first ~75.5 MB; all dead before final logits GEMM
  // rewrites the full logits region in f32.
  char* ob = (char*)d_out;
  float*  x   = (float*)ob;                                  // f32 [NTOK][ND], 25.2 MB
  ushort* qb  = (ushort*)(ob + 25165824);                    // bf16 [NTOK][ND]
  ushort* kb  = (ushort*)(ob + 25165824 + 12582912);
  ushort* vb  = (ushort*)(ob + 25165824 + 2 * 12582912);
  ushort* mid = (ushort*)(ob + 25165824);                    // bf16 [NTOK][NFF] (FF phase)
  float* logits = (float*)d_out;

  char* ws = (char*)d_ws;
  size_t off = 0;
  auto alloc = [&](size_t bytes) -> void* {
    void* p = ws + off; off += (bytes + 255) & ~(size_t)255; return p;
  };
  ushort* h    = (ushort*)alloc((size_t)NTOK * ND * 2);
  ushort* wqT  = (ushort*)alloc((size_t)ND * ND * 2);
  ushort* wkT  = (ushort*)alloc((size_t)ND * ND * 2);
  ushort* wvT  = (ushort*)alloc((size_t)ND * ND * 2);
  ushort* wpT  = (ushort*)alloc((size_t)ND * ND * 2);
  ushort* w1T  = (ushort*)alloc((size_t)ND * NFF * 2);
  ushort* w2T  = (ushort*)alloc((size_t)ND * NFF * 2);
  ushort* wlmT = (ushort*)alloc((size_t)ND * NV * 2);
  float*  rowloss = (float*)alloc((size_t)NTOK * 4);

  embed_kernel<<<NTOK, 192, 0, stream>>>(idx, tok, pos, x);

  const int tqkv = NH * ND * NDH;
  const int tpp  = ND * ND;
  const int tff  = ND * NFF;
  dim3 g768(ND / 128, NTOK / 128);
  dim3 gff(NFF / 128, NTOK / 128);

  for (int l = 0; l < NL; ++l) {
    transp_conv<<<(tqkv + 255) / 256, 256, 0, stream>>>(Wq + (size_t)l * tqkv, wqT, ND, NDH, tqkv);
    transp_conv<<<(tqkv + 255) / 256, 256, 0, stream>>>(Wk + (size_t)l * tqkv, wkT, ND, NDH, tqkv);
    transp_conv<<<(tqkv + 255) / 256, 256, 0, stream>>>(Wv + (size_t)l * tqkv, wvT, ND, NDH, tqkv);
    transp_conv<<<(tpp + 255) / 256, 256, 0, stream>>>(Wp + (size_t)l * tpp, wpT, ND, ND, tpp);
    transp_conv<<<(tff + 255) / 256, 256, 0, stream>>>(W1 + (size_t)l * tff, w1T, ND, NFF, tff);
    transp_conv<<<(tff + 255) / 256, 256, 0, stream>>>(W2 + (size_t)l * tff, w2T, NFF, ND, tff);

    ln_kernel<<<NTOK, 256, 0, stream>>>(x, ln1g + l * ND, ln1b + l * ND, h);
    gemm_bt<false,false,false,1><<<g768, 256, 0, stream>>>(h, wqT, nullptr, nullptr, qb, NTOK, ND, ND);
    gemm_bt<false,false,false,1><<<g768, 256, 0, stream>>>(h, wkT, nullptr, nullptr, kb, NTOK, ND, ND);
    gemm_bt<false,false,false,1><<<g768, 256, 0, stream>>>(h, wvT, nullptr, nullptr, vb, NTOK, ND, ND);
    attn_naive<<<NB * NH * (NT / 4), 256, 0, stream>>>(qb, kb, vb, h);
    gemm_bt<true,false,true,0><<<g768, 256, 0, stream>>>(h, wpT, bp + l * ND, x, nullptr, NTOK, ND, ND);
    ln_kernel<<<NTOK, 256, 0, stream>>>(x, ln2g + l * ND, ln2b + l * ND, h);
    gemm_bt<true,true,false,1><<<gff, 256, 0, stream>>>(h, w1T, b1 + (size_t)l * NFF, nullptr, mid, NTOK, NFF, ND);
    gemm_bt<true,false,true,0><<<g768, 256, 0, stream>>>(mid, w2T, b2 + l * ND, x, nullptr, NTOK, ND, NFF);
  }

  ln_kernel<<<NTOK, 256, 0, stream>>>(x, lnfg, lnfb, h);
  const int tlm = ND * NV;
  transp_conv<<<(tlm + 255) / 256, 256, 0, stream>>>(Wlm, wlmT, ND, NV, tlm);
  dim3 glm(NV / 128, NTOK / 128);
  gemm_bt<true,false,false,2><<<glm, 256, 0, stream>>>(h, wlmT, blm, nullptr, logits, NTOK, NV, ND);

  loss_row<<<NTOK, 256, 0, stream>>>(logits, targets, rowloss);
  loss_reduce<<<1, 256, 0, stream>>>(rowloss, logits + (size_t)NTOK * NV);
}

// Round 6
// 3033.194 us; speedup vs baseline: 3.5810x; 3.5810x over previous
//
#include <hip/hip_runtime.h>
#include <hip/hip_bf16.h>

typedef unsigned int uint;
typedef unsigned short ushort;

typedef short s16x8 __attribute__((ext_vector_type(8)));
typedef float f32x4 __attribute__((ext_vector_type(4)));
typedef uint  u32x4 __attribute__((ext_vector_type(4)));

#define NB 8
#define NT 1024
#define NV 8192
#define ND 768
#define NH 12
#define NL 6
#define NDH 64
#define NFF 3072
#define NTOK (NB*NT)

__device__ __forceinline__ ushort f2bf(float f) {
  uint x = __float_as_uint(f);
  x += 0x7FFFu + ((x >> 16) & 1u);
  return (ushort)(x >> 16);
}
__device__ __forceinline__ float bf2f(ushort u) {
  return __uint_as_float(((uint)u) << 16);
}

// XOR swizzle within a 64-ushort (128B) row: 16B chunk index ^= row&7
__device__ __forceinline__ int swz(int row, int col) {
  return row * 64 + ((((col >> 3) ^ row) & 7) << 3) + (col & 7);
}

// ---------------- embed ----------------
__global__ __launch_bounds__(192) void embed_kernel(
    const int* __restrict__ idx, const float* __restrict__ tok,
    const float* __restrict__ pos, float* __restrict__ x)
{
  int n = blockIdx.x, t = threadIdx.x;
  int token = idx[n];
  const float4* tp = (const float4*)(tok + (size_t)token * ND);
  const float4* pp = (const float4*)(pos + (size_t)(n & (NT - 1)) * ND);
  float4 a = tp[t], b = pp[t];
  float4 r; r.x = a.x + b.x; r.y = a.y + b.y; r.z = a.z + b.z; r.w = a.w + b.w;
  ((float4*)(x + (size_t)n * ND))[t] = r;
}

// ---------------- layernorm (f32 in -> bf16 out) ----------------
__global__ __launch_bounds__(256) void ln_kernel(
    const float* __restrict__ x, const float* __restrict__ g,
    const float* __restrict__ b, ushort* __restrict__ out)
{
  int row = blockIdx.x, tid = threadIdx.x;
  const float* xr = x + (size_t)row * ND;
  float v0 = xr[tid], v1 = xr[tid + 256], v2 = xr[tid + 512];
  float s = v0 + v1 + v2;
  float q = v0 * v0 + v1 * v1 + v2 * v2;
  #pragma unroll
  for (int d = 1; d < 64; d <<= 1) { s += __shfl_xor(s, d); q += __shfl_xor(q, d); }
  __shared__ float rs[4], rq[4];
  int w = tid >> 6;
  if ((tid & 63) == 0) { rs[w] = s; rq[w] = q; }
  __syncthreads();
  s = rs[0] + rs[1] + rs[2] + rs[3];
  q = rq[0] + rq[1] + rq[2] + rq[3];
  float mean = s * (1.0f / ND);
  float inv = rsqrtf(q * (1.0f / ND) - mean * mean + 1e-5f);
  ushort* orow = out + (size_t)row * ND;
  orow[tid]       = f2bf((v0 - mean) * inv * g[tid]       + b[tid]);
  orow[tid + 256] = f2bf((v1 - mean) * inv * g[tid + 256] + b[tid + 256]);
  orow[tid + 512] = f2bf((v2 - mean) * inv * g[tid + 512] + b[tid + 512]);
}

// ---------------- transpose + f32->bf16 convert ----------------
__global__ __launch_bounds__(256) void transp_conv(
    const float* __restrict__ in, ushort* __restrict__ out, int R, int C, int total)
{
  int o = blockIdx.x * 256 + threadIdx.x;
  if (o >= total) return;
  int rc = R * C;
  int bi = o / rc;
  int rem = o - bi * rc;
  int c = rem / R;
  int r = rem - c * R;
  out[o] = f2bf(in[(size_t)bi * rc + (size_t)r * C + c]);
}

// ---------------- bf16 MFMA GEMM: C[M,N] = A[M,K] @ Bt[N,K]^T ----------------
// OUT: 0 = none, 1 = bf16, 2 = f32
template<bool BIAS, bool RELU, bool RESID, int OUT>
__global__ __launch_bounds__(256) void gemm_bt(
    const ushort* __restrict__ A, const ushort* __restrict__ Bt,
    const float* __restrict__ bias, float* __restrict__ xres,
    void* __restrict__ outp, int M, int N, int K)
{
  __shared__ ushort As[128][48];
  __shared__ ushort Bs[128][48];
  const int tid = threadIdx.x;
  const int lane = tid & 63;
  const int w = tid >> 6;
  const int wr = w >> 1, wc = w & 1;
  const int lg = lane >> 4, li = lane & 15;
  const int m0 = blockIdx.y * 128, n0 = blockIdx.x * 128;
  const int sr = tid >> 2, sc = (tid & 3) * 8;

  f32x4 acc[4][4];
  #pragma unroll
  for (int i = 0; i < 4; ++i)
    #pragma unroll
    for (int j = 0; j < 4; ++j) { f32x4 z = {0.f,0.f,0.f,0.f}; acc[i][j] = z; }

  for (int kk = 0; kk < K; kk += 32) {
    __syncthreads();
    #pragma unroll
    for (int p = 0; p < 2; ++p) {
      int r = p * 64 + sr;
      *(u32x4*)&As[r][sc] = *(const u32x4*)&A[(size_t)(m0 + r) * K + kk + sc];
      *(u32x4*)&Bs[r][sc] = *(const u32x4*)&Bt[(size_t)(n0 + r) * K + kk + sc];
    }
    __syncthreads();
    s16x8 af[4], bfr[4];
    #pragma unroll
    for (int i = 0; i < 4; ++i) {
      af[i]  = *(const s16x8*)&As[wr * 64 + i * 16 + li][lg * 8];
      bfr[i] = *(const s16x8*)&Bs[wc * 64 + i * 16 + li][lg * 8];
    }
    #pragma unroll
    for (int i = 0; i < 4; ++i)
      #pragma unroll
      for (int j = 0; j < 4; ++j)
        acc[i][j] = __builtin_amdgcn_mfma_f32_16x16x32_bf16(af[i], bfr[j], acc[i][j], 0, 0, 0);
  }

  #pragma unroll
  for (int i = 0; i < 4; ++i) {
    #pragma unroll
    for (int j = 0; j < 4; ++j) {
      int row0 = m0 + wr * 64 + i * 16 + lg * 4;
      int col  = n0 + wc * 64 + j * 16 + li;
      float bv = BIAS ? bias[col] : 0.f;
      #pragma unroll
      for (int ii = 0; ii < 4; ++ii) {
        float val = acc[i][j][ii] + bv;
        if (RELU) val = fmaxf(val, 0.f);
        size_t off = (size_t)(row0 + ii) * N + col;
        if (RESID) { val += xres[off]; xres[off] = val; }
        if (OUT == 1) ((ushort*)outp)[off] = f2bf(val);
        if (OUT == 2) ((float*)outp)[off] = val;
      }
    }
  }
}

// ---------------- MFMA causal flash attention ----------------
// q,k,v: [NTOK][ND] bf16 (col = h*64+e). o: same layout. 4 waves = 64 q rows/block.
__global__ __launch_bounds__(256) void attn_kernel(
    const ushort* __restrict__ q, const ushort* __restrict__ k,
    const ushort* __restrict__ v, ushort* __restrict__ o)
{
  __shared__ ushort Ks[64 * 64];     // [key][dh], swizzled
  __shared__ ushort Vt[64 * 64];     // [dh][key], swizzled
  __shared__ ushort Ps[4][16 * 64];  // per-wave P [qrow][key], swizzled

  const int tid = threadIdx.x;
  const int lane = tid & 63;
  const int w = tid >> 6;
  const int lg = lane >> 4;
  const int li = lane & 15;

  int bid = blockIdx.x;
  const int qt = bid & 15;
  const int h = (bid >> 4) % NH;
  const int b = bid / (16 * NH);
  const int q0 = qt * 64 + w * 16;
  const size_t nbase = (size_t)b * NT;

  s16x8 aq[2];
  #pragma unroll
  for (int c = 0; c < 2; ++c)
    aq[c] = *(const s16x8*)&q[(nbase + q0 + li) * ND + h * NDH + c * 32 + lg * 8];

  float m_r[4], l_r[4];
  f32x4 oacc[4];
  #pragma unroll
  for (int i = 0; i < 4; ++i) { m_r[i] = -1e30f; l_r[i] = 0.f; }
  #pragma unroll
  for (int f = 0; f < 4; ++f) { f32x4 z = {0.f,0.f,0.f,0.f}; oacc[f] = z; }

  const float scale = 0.036084391824351615f;  // 768^-0.5 (reference uses D, not DH)

  const int nkc = qt + 1;
  for (int kc = 0; kc < nkc; ++kc) {
    #pragma unroll
    for (int p = 0; p < 2; ++p) {
      int id2 = p * 256 + tid;
      int key = id2 >> 3, c8 = (id2 & 7) * 8;
      size_t goff = (nbase + kc * 64 + key) * ND + h * NDH + c8;
      u32x4 kvv = *(const u32x4*)&k[goff];
      *(u32x4*)&Ks[swz(key, c8)] = kvv;
      u32x4 vvv = *(const u32x4*)&v[goff];
      ushort* vp = (ushort*)&vvv;
      #pragma unroll
      for (int j = 0; j < 8; ++j) Vt[swz(c8 + j, key)] = vp[j];
    }
    __syncthreads();
    // QK^T: C row = q row (lg*4+i), col = key (kt*16+li)
    f32x4 s[4];
    #pragma unroll
    for (int kt = 0; kt < 4; ++kt) {
      f32x4 z = {0.f,0.f,0.f,0.f}; s[kt] = z;
      #pragma unroll
      for (int c = 0; c < 2; ++c) {
        s16x8 bk = *(const s16x8*)&Ks[swz(kt * 16 + li, c * 32 + lg * 8)];
        s[kt] = __builtin_amdgcn_mfma_f32_16x16x32_bf16(aq[c], bk, s[kt], 0, 0, 0);
      }
    }
    // online softmax per q row
    #pragma unroll
    for (int i = 0; i < 4; ++i) {
      int row = q0 + lg * 4 + i;
      float sv[4]; float mx = -1e30f;
      #pragma unroll
      for (int kt = 0; kt < 4; ++kt) {
        int key = kc * 64 + kt * 16 + li;
        float t = s[kt][i] * scale;
        t = (key <= row) ? t : -1e30f;
        sv[kt] = t; mx = fmaxf(mx, t);
      }
      #pragma unroll
      for (int d = 1; d < 16; d <<= 1) mx = fmaxf(mx, __shfl_xor(mx, d));
      float mnew = fmaxf(m_r[i], mx);
      float corr = __expf(m_r[i] - mnew);
      float ps = 0.f;
      #pragma unroll
      for (int kt = 0; kt < 4; ++kt) {
        float pe = __expf(sv[kt] - mnew);
        ps += pe;
        Ps[w][swz(lg * 4 + i, kt * 16 + li)] = f2bf(pe);
      }
      #pragma unroll
      for (int d = 1; d < 16; d <<= 1) ps += __shfl_xor(ps, d);
      l_r[i] = l_r[i] * corr + ps;
      m_r[i] = mnew;
      #pragma unroll
      for (int f = 0; f < 4; ++f) oacc[f][i] *= corr;
    }
    // PV: A = P [qrow][key], B^T = Vt [dh][key]; C col = dh (f*16+li), row = qrow
    #pragma unroll
    for (int f = 0; f < 4; ++f) {
      #pragma unroll
      for (int c = 0; c < 2; ++c) {
        s16x8 ap = *(const s16x8*)&Ps[w][swz(li, c * 32 + lg * 8)];
        s16x8 bv = *(const s16x8*)&Vt[swz(f * 16 + li, c * 32 + lg * 8)];
        oacc[f] = __builtin_amdgcn_mfma_f32_16x16x32_bf16(ap, bv, oacc[f], 0, 0, 0);
      }
    }
    __syncthreads();
  }
  #pragma unroll
  for (int f = 0; f < 4; ++f)
    #pragma unroll
    for (int i = 0; i < 4; ++i) {
      float val = oacc[f][i] / l_r[i];
      o[(nbase + q0 + lg * 4 + i) * ND + h * NDH + f * 16 + li] = f2bf(val);
    }
}

// ---------------- loss (f32 logits), deterministic two-stage ----------------
__global__ __launch_bounds__(256) void loss_row(
    const float* __restrict__ logits, const int* __restrict__ targets,
    float* __restrict__ rowloss)
{
  int row = blockIdx.x, tid = threadIdx.x;
  const float* lr = logits + (size_t)row * NV;
  const float4* l4 = (const float4*)lr;
  float vals[32];
  float mx = -1e30f;
  #pragma unroll
  for (int p = 0; p < 8; ++p) {
    float4 t = l4[p * 256 + tid];
    vals[p*4+0] = t.x; vals[p*4+1] = t.y; vals[p*4+2] = t.z; vals[p*4+3] = t.w;
    mx = fmaxf(mx, fmaxf(fmaxf(t.x, t.y), fmaxf(t.z, t.w)));
  }
  #pragma unroll
  for (int d = 1; d < 64; d <<= 1) mx = fmaxf(mx, __shfl_xor(mx, d));
  __shared__ float red[4], red2[4];
  int w = tid >> 6, lane = tid & 63;
  if (lane == 0) red[w] = mx;
  __syncthreads();
  mx = fmaxf(fmaxf(red[0], red[1]), fmaxf(red[2], red[3]));
  float sm = 0.f;
  #pragma unroll
  for (int i = 0; i < 32; ++i) sm += __expf(vals[i] - mx);
  #pragma unroll
  for (int d = 1; d < 64; d <<= 1) sm += __shfl_xor(sm, d);
  if (lane == 0) red2[w] = sm;
  __syncthreads();
  if (tid == 0) {
    float total = red2[0] + red2[1] + red2[2] + red2[3];
    float lse = mx + __logf(total);
    rowloss[row] = lse - lr[targets[row]];
  }
}

__global__ __launch_bounds__(256) void loss_reduce(
    const float* __restrict__ rowloss, float* __restrict__ out_loss)
{
  int tid = threadIdx.x;
  float s = 0.f;
  #pragma unroll
  for (int i = 0; i < 32; ++i) s += rowloss[tid + i * 256];
  #pragma unroll
  for (int d = 1; d < 64; d <<= 1) s += __shfl_xor(s, d);
  __shared__ float red[4];
  int w = tid >> 6, lane = tid & 63;
  if (lane == 0) red[w] = s;
  __syncthreads();
  if (tid == 0) {
    float total = red[0] + red[1] + red[2] + red[3];
    out_loss[0] = total * (1.0f / NTOK);
  }
}

// ---------------- launch ----------------
extern "C" void kernel_launch(void* const* d_in, const int* in_sizes, int n_in,
                              void* d_out, int out_size, void* d_ws, size_t ws_size,
                              hipStream_t stream)
{
  const int*   idx     = (const int*)d_in[0];
  const int*   targets = (const int*)d_in[1];
  const float* tok     = (const float*)d_in[2];
  const float* pos     = (const float*)d_in[3];
  const float* ln1g    = (const float*)d_in[4];
  const float* ln1b    = (const float*)d_in[5];
  const float* Wq      = (const float*)d_in[6];
  const float* Wk      = (const float*)d_in[7];
  const float* Wv      = (const float*)d_in[8];
  const float* Wp      = (const float*)d_in[9];
  const float* bp      = (const float*)d_in[10];
  const float* ln2g    = (const float*)d_in[11];
  const float* ln2b    = (const float*)d_in[12];
  const float* W1      = (const float*)d_in[13];
  const float* b1      = (const float*)d_in[14];
  const float* W2      = (const float*)d_in[15];
  const float* b2      = (const float*)d_in[16];
  const float* lnfg    = (const float*)d_in[17];
  const float* lnfb    = (const float*)d_in[18];
  const float* Wlm     = (const float*)d_in[19];
  const float* blm     = (const float*)d_in[20];

  // d_out is FLOAT32: out_size = NTOK*NV + 1 elements = 268,435,460 bytes.
  // Scratch phase uses first ~75.5 MB; all dead before final logits GEMM
  // rewrites the full logits region in f32.
  char* ob = (char*)d_out;
  float*  x   = (float*)ob;                                  // f32 [NTOK][ND], 25.2 MB
  ushort* qb  = (ushort*)(ob + 25165824);                    // bf16 [NTOK][ND]
  ushort* kb  = (ushort*)(ob + 25165824 + 12582912);
  ushort* vb  = (ushort*)(ob + 25165824 + 2 * 12582912);
  ushort* mid = (ushort*)(ob + 25165824);                    // bf16 [NTOK][NFF] (FF phase)
  float* logits = (float*)d_out;

  char* ws = (char*)d_ws;
  size_t off = 0;
  auto alloc = [&](size_t bytes) -> void* {
    void* p = ws + off; off += (bytes + 255) & ~(size_t)255; return p;
  };
  ushort* h    = (ushort*)alloc((size_t)NTOK * ND * 2);
  ushort* wqT  = (ushort*)alloc((size_t)ND * ND * 2);
  ushort* wkT  = (ushort*)alloc((size_t)ND * ND * 2);
  ushort* wvT  = (ushort*)alloc((size_t)ND * ND * 2);
  ushort* wpT  = (ushort*)alloc((size_t)ND * ND * 2);
  ushort* w1T  = (ushort*)alloc((size_t)ND * NFF * 2);
  ushort* w2T  = (ushort*)alloc((size_t)ND * NFF * 2);
  ushort* wlmT = (ushort*)alloc((size_t)ND * NV * 2);
  float*  rowloss = (float*)alloc((size_t)NTOK * 4);

  embed_kernel<<<NTOK, 192, 0, stream>>>(idx, tok, pos, x);

  const int tqkv = NH * ND * NDH;
  const int tpp  = ND * ND;
  const int tff  = ND * NFF;
  dim3 g768(ND / 128, NTOK / 128);
  dim3 gff(NFF / 128, NTOK / 128);

  for (int l = 0; l < NL; ++l) {
    transp_conv<<<(tqkv + 255) / 256, 256, 0, stream>>>(Wq + (size_t)l * tqkv, wqT, ND, NDH, tqkv);
    transp_conv<<<(tqkv + 255) / 256, 256, 0, stream>>>(Wk + (size_t)l * tqkv, wkT, ND, NDH, tqkv);
    transp_conv<<<(tqkv + 255) / 256, 256, 0, stream>>>(Wv + (size_t)l * tqkv, wvT, ND, NDH, tqkv);
    transp_conv<<<(tpp + 255) / 256, 256, 0, stream>>>(Wp + (size_t)l * tpp, wpT, ND, ND, tpp);
    transp_conv<<<(tff + 255) / 256, 256, 0, stream>>>(W1 + (size_t)l * tff, w1T, ND, NFF, tff);
    transp_conv<<<(tff + 255) / 256, 256, 0, stream>>>(W2 + (size_t)l * tff, w2T, NFF, ND, tff);

    ln_kernel<<<NTOK, 256, 0, stream>>>(x, ln1g + l * ND, ln1b + l * ND, h);
    gemm_bt<false,false,false,1><<<g768, 256, 0, stream>>>(h, wqT, nullptr, nullptr, qb, NTOK, ND, ND);
    gemm_bt<false,false,false,1><<<g768, 256, 0, stream>>>(h, wkT, nullptr, nullptr, kb, NTOK, ND, ND);
    gemm_bt<false,false,false,1><<<g768, 256, 0, stream>>>(h, wvT, nullptr, nullptr, vb, NTOK, ND, ND);
    attn_kernel<<<NB * NH * (NT / 64), 256, 0, stream>>>(qb, kb, vb, h);
    gemm_bt<true,false,true,0><<<g768, 256, 0, stream>>>(h, wpT, bp + l * ND, x, nullptr, NTOK, ND, ND);
    ln_kernel<<<NTOK, 256, 0, stream>>>(x, ln2g + l * ND, ln2b + l * ND, h);
    gemm_bt<true,true,false,1><<<gff, 256, 0, stream>>>(h, w1T, b1 + (size_t)l * NFF, nullptr, mid, NTOK, NFF, ND);
    gemm_bt<true,false,true,0><<<g768, 256, 0, stream>>>(mid, w2T, b2 + l * ND, x, nullptr, NTOK, ND, NFF);
  }

  ln_kernel<<<NTOK, 256, 0, stream>>>(x, lnfg, lnfb, h);
  const int tlm = ND * NV;
  transp_conv<<<(tlm + 255) / 256, 256, 0, stream>>>(Wlm, wlmT, ND, NV, tlm);
  dim3 glm(NV / 128, NTOK / 128);
  gemm_bt<true,false,false,2><<<glm, 256, 0, stream>>>(h, wlmT, blm, nullptr, logits, NTOK, NV, ND);

  loss_row<<<NTOK, 256, 0, stream>>>(logits, targets, rowloss);
  loss_reduce<<<1, 256, 0, stream>>>(rowloss, logits + (size_t)NTOK * NV);
}

// Round 7
// 2754.519 us; speedup vs baseline: 3.9432x; 1.1012x over previous
//
#include <hip/hip_runtime.h>
#include <hip/hip_bf16.h>

typedef unsigned int uint;
typedef unsigned short ushort;

typedef short s16x8 __attribute__((ext_vector_type(8)));
typedef float f32x4 __attribute__((ext_vector_type(4)));
typedef uint  u32x4 __attribute__((ext_vector_type(4)));

#define NB 8
#define NT 1024
#define NV 8192
#define ND 768
#define NH 12
#define NL 6
#define NDH 64
#define NFF 3072
#define NTOK (NB*NT)

__device__ __forceinline__ ushort f2bf(float f) {
  uint x = __float_as_uint(f);
  x += 0x7FFFu + ((x >> 16) & 1u);
  return (ushort)(x >> 16);
}
__device__ __forceinline__ float bf2f(ushort u) {
  return __uint_as_float(((uint)u) << 16);
}

// XOR swizzle within a 64-ushort (128B) row: 16B chunk index ^= row&7
__device__ __forceinline__ int swz(int row, int col) {
  return row * 64 + ((((col >> 3) ^ row) & 7) << 3) + (col & 7);
}

// async global->LDS, 16B per lane, dest = wave-uniform base + lane*16
__device__ __forceinline__ void gload16(const ushort* g, ushort* l) {
  __builtin_amdgcn_global_load_lds(
      (const __attribute__((address_space(1))) void*)g,
      (__attribute__((address_space(3))) void*)l, 16, 0, 0);
}

// ---------------- embed ----------------
__global__ __launch_bounds__(192) void embed_kernel(
    const int* __restrict__ idx, const float* __restrict__ tok,
    const float* __restrict__ pos, float* __restrict__ x)
{
  int n = blockIdx.x, t = threadIdx.x;
  int token = idx[n];
  const float4* tp = (const float4*)(tok + (size_t)token * ND);
  const float4* pp = (const float4*)(pos + (size_t)(n & (NT - 1)) * ND);
  float4 a = tp[t], b = pp[t];
  float4 r; r.x = a.x + b.x; r.y = a.y + b.y; r.z = a.z + b.z; r.w = a.w + b.w;
  ((float4*)(x + (size_t)n * ND))[t] = r;
}

// ---------------- layernorm (f32 in -> bf16 out) ----------------
__global__ __launch_bounds__(256) void ln_kernel(
    const float* __restrict__ x, const float* __restrict__ g,
    const float* __restrict__ b, ushort* __restrict__ out)
{
  int row = blockIdx.x, tid = threadIdx.x;
  const float* xr = x + (size_t)row * ND;
  float v0 = xr[tid], v1 = xr[tid + 256], v2 = xr[tid + 512];
  float s = v0 + v1 + v2;
  float q = v0 * v0 + v1 * v1 + v2 * v2;
  #pragma unroll
  for (int d = 1; d < 64; d <<= 1) { s += __shfl_xor(s, d); q += __shfl_xor(q, d); }
  __shared__ float rs[4], rq[4];
  int w = tid >> 6;
  if ((tid & 63) == 0) { rs[w] = s; rq[w] = q; }
  __syncthreads();
  s = rs[0] + rs[1] + rs[2] + rs[3];
  q = rq[0] + rq[1] + rq[2] + rq[3];
  float mean = s * (1.0f / ND);
  float inv = rsqrtf(q * (1.0f / ND) - mean * mean + 1e-5f);
  ushort* orow = out + (size_t)row * ND;
  orow[tid]       = f2bf((v0 - mean) * inv * g[tid]       + b[tid]);
  orow[tid + 256] = f2bf((v1 - mean) * inv * g[tid + 256] + b[tid + 256]);
  orow[tid + 512] = f2bf((v2 - mean) * inv * g[tid + 512] + b[tid + 512]);
}

// ------- batched transpose + f32->bf16: out[(bi/HB)*sl + (bi%HB)*sh + c*R+r] = in[bi][r][c]
__global__ __launch_bounds__(256) void transp2(
    const float* __restrict__ in, ushort* __restrict__ out, int R, int C,
    int HB, size_t sh, size_t sl, int total)
{
  int o = blockIdx.x * 256 + threadIdx.x;
  if (o >= total) return;
  int rc = R * C;
  int bi = o / rc;
  int rem = o - bi * rc;
  int c = rem / R;
  int r = rem - c * R;
  out[(size_t)(bi / HB) * sl + (size_t)(bi % HB) * sh + rem] =
      f2bf(in[(size_t)bi * rc + (size_t)r * C + c]);
}

// ---------------- bf16 MFMA GEMM (m97 structure): C[M,N] = A[M,K] @ Bt[N,K]^T
// OUT: 0 = none, 1 = bf16, 2 = f32
template<bool BIAS, bool RELU, bool RESID, int OUT>
__global__ __launch_bounds__(256) void gemm_bt(
    const ushort* __restrict__ A, const ushort* __restrict__ Bt,
    const float* __restrict__ bias, float* __restrict__ xres,
    void* __restrict__ outp, int M, int N, int K)
{
  __shared__ ushort As[4096];  // [128][32] linear (gload_lds: no padding allowed)
  __shared__ ushort Bs[4096];
  const int tid = threadIdx.x;
  const int lane = tid & 63;
  const int w = tid >> 6;
  const int wr = w >> 1, wc = w & 1;
  const int lg = lane >> 4, li = lane & 15;
  const int m0 = blockIdx.y * 128, n0 = blockIdx.x * 128;

  // per-lane global srcs (lane covers row tid/4, k-chunk (tid&3)*8)
  const ushort* gA = &A[(size_t)(m0 + (tid >> 2)) * K + (tid & 3) * 8];
  const ushort* gB = &Bt[(size_t)(n0 + (tid >> 2)) * K + (tid & 3) * 8];
  const size_t rowK64 = (size_t)64 * K;
  // wave-uniform LDS dests: wave w stages rows w*16..w*16+15 of each half
  ushort* lA0 = &As[w * 512];
  ushort* lA1 = &As[2048 + w * 512];
  ushort* lB0 = &Bs[w * 512];
  ushort* lB1 = &Bs[2048 + w * 512];

  f32x4 acc[4][4];
  #pragma unroll
  for (int i = 0; i < 4; ++i)
    #pragma unroll
    for (int j = 0; j < 4; ++j) { f32x4 z = {0.f,0.f,0.f,0.f}; acc[i][j] = z; }

  for (int kk = 0; kk < K; kk += 32) {
    __syncthreads();
    gload16(gA + kk, lA0);
    gload16(gA + kk + rowK64, lA1);
    gload16(gB + kk, lB0);
    gload16(gB + kk + rowK64, lB1);
    __syncthreads();   // compiler drains vmcnt(0) before barrier
    s16x8 af[4], bfr[4];
    #pragma unroll
    for (int i = 0; i < 4; ++i) {
      af[i]  = *(const s16x8*)&As[(wr * 64 + i * 16 + li) * 32 + lg * 8];
      bfr[i] = *(const s16x8*)&Bs[(wc * 64 + i * 16 + li) * 32 + lg * 8];
    }
    #pragma unroll
    for (int i = 0; i < 4; ++i)
      #pragma unroll
      for (int j = 0; j < 4; ++j)
        acc[i][j] = __builtin_amdgcn_mfma_f32_16x16x32_bf16(af[i], bfr[j], acc[i][j], 0, 0, 0);
  }

  #pragma unroll
  for (int i = 0; i < 4; ++i) {
    #pragma unroll
    for (int j = 0; j < 4; ++j) {
      int row0 = m0 + wr * 64 + i * 16 + lg * 4;
      int col  = n0 + wc * 64 + j * 16 + li;
      float bv = BIAS ? bias[col] : 0.f;
      #pragma unroll
      for (int ii = 0; ii < 4; ++ii) {
        float val = acc[i][j][ii] + bv;
        if (RELU) val = fmaxf(val, 0.f);
        size_t off = (size_t)(row0 + ii) * N + col;
        if (RESID) { val += xres[off]; xres[off] = val; }
        if (OUT == 1) ((ushort*)outp)[off] = f2bf(val);
        if (OUT == 2) ((float*)outp)[off] = val;
      }
    }
  }
}

// ---------------- MFMA causal flash attention ----------------
// qkv: [NTOK][2304] bf16 (q: col h*64, k: 768+h*64, v: 1536+h*64). o: [NTOK][768].
__global__ __launch_bounds__(256) void attn_kernel(
    const ushort* __restrict__ qkv, ushort* __restrict__ o)
{
  __shared__ ushort Ks[64 * 64];     // [key][dh], swizzled
  __shared__ ushort Vt[64 * 64];     // [dh][key], swizzled
  __shared__ ushort Ps[4][16 * 64];  // per-wave P [qrow][key], swizzled

  const int tid = threadIdx.x;
  const int lane = tid & 63;
  const int w = tid >> 6;
  const int lg = lane >> 4;
  const int li = lane & 15;

  int bid = blockIdx.x;
  const int qt = bid & 15;
  const int h = (bid >> 4) % NH;
  const int b = bid / (16 * NH);
  const int q0 = qt * 64 + w * 16;
  const size_t nbase = (size_t)b * NT;
  const int hq = h * NDH;
  const int hk = ND + h * NDH;
  const int hv = 2 * ND + h * NDH;

  s16x8 aq[2];
  #pragma unroll
  for (int c = 0; c < 2; ++c)
    aq[c] = *(const s16x8*)&qkv[(nbase + q0 + li) * (3 * ND) + hq + c * 32 + lg * 8];

  float m_r[4], l_r[4];
  f32x4 oacc[4];
  #pragma unroll
  for (int i = 0; i < 4; ++i) { m_r[i] = -1e30f; l_r[i] = 0.f; }
  #pragma unroll
  for (int f = 0; f < 4; ++f) { f32x4 z = {0.f,0.f,0.f,0.f}; oacc[f] = z; }

  const float scale = 0.036084391824351615f;  // 768^-0.5 (reference uses D, not DH)

  const int nkc = qt + 1;
  for (int kc = 0; kc < nkc; ++kc) {
    #pragma unroll
    for (int p = 0; p < 2; ++p) {
      int id2 = p * 256 + tid;
      int key = id2 >> 3, c8 = (id2 & 7) * 8;
      size_t rb = (nbase + kc * 64 + key) * (size_t)(3 * ND);
      u32x4 kvv = *(const u32x4*)&qkv[rb + hk + c8];
      *(u32x4*)&Ks[swz(key, c8)] = kvv;
      u32x4 vvv = *(const u32x4*)&qkv[rb + hv + c8];
      ushort* vp = (ushort*)&vvv;
      #pragma unroll
      for (int j = 0; j < 8; ++j) Vt[swz(c8 + j, key)] = vp[j];
    }
    __syncthreads();
    // QK^T: C row = q row (lg*4+i), col = key (kt*16+li)
    f32x4 s[4];
    #pragma unroll
    for (int kt = 0; kt < 4; ++kt) {
      f32x4 z = {0.f,0.f,0.f,0.f}; s[kt] = z;
      #pragma unroll
      for (int c = 0; c < 2; ++c) {
        s16x8 bk = *(const s16x8*)&Ks[swz(kt * 16 + li, c * 32 + lg * 8)];
        s[kt] = __builtin_amdgcn_mfma_f32_16x16x32_bf16(aq[c], bk, s[kt], 0, 0, 0);
      }
    }
    // online softmax per q row
    #pragma unroll
    for (int i = 0; i < 4; ++i) {
      int row = q0 + lg * 4 + i;
      float sv[4]; float mx = -1e30f;
      #pragma unroll
      for (int kt = 0; kt < 4; ++kt) {
        int key = kc * 64 + kt * 16 + li;
        float t = s[kt][i] * scale;
        t = (key <= row) ? t : -1e30f;
        sv[kt] = t; mx = fmaxf(mx, t);
      }
      #pragma unroll
      for (int d = 1; d < 16; d <<= 1) mx = fmaxf(mx, __shfl_xor(mx, d));
      float mnew = fmaxf(m_r[i], mx);
      float corr = __expf(m_r[i] - mnew);
      float ps = 0.f;
      #pragma unroll
      for (int kt = 0; kt < 4; ++kt) {
        float pe = __expf(sv[kt] - mnew);
        ps += pe;
        Ps[w][swz(lg * 4 + i, kt * 16 + li)] = f2bf(pe);
      }
      #pragma unroll
      for (int d = 1; d < 16; d <<= 1) ps += __shfl_xor(ps, d);
      l_r[i] = l_r[i] * corr + ps;
      m_r[i] = mnew;
      #pragma unroll
      for (int f = 0; f < 4; ++f) oacc[f][i] *= corr;
    }
    // PV: A = P [qrow][key], B^T = Vt [dh][key]
    #pragma unroll
    for (int f = 0; f < 4; ++f) {
      #pragma unroll
      for (int c = 0; c < 2; ++c) {
        s16x8 ap = *(const s16x8*)&Ps[w][swz(li, c * 32 + lg * 8)];
        s16x8 bv = *(const s16x8*)&Vt[swz(f * 16 + li, c * 32 + lg * 8)];
        oacc[f] = __builtin_amdgcn_mfma_f32_16x16x32_bf16(ap, bv, oacc[f], 0, 0, 0);
      }
    }
    __syncthreads();
  }
  #pragma unroll
  for (int f = 0; f < 4; ++f)
    #pragma unroll
    for (int i = 0; i < 4; ++i) {
      float val = oacc[f][i] / l_r[i];
      o[(nbase + q0 + lg * 4 + i) * ND + h * NDH + f * 16 + li] = f2bf(val);
    }
}

// ---------------- loss (f32 logits), deterministic two-stage ----------------
__global__ __launch_bounds__(256) void loss_row(
    const float* __restrict__ logits, const int* __restrict__ targets,
    float* __restrict__ rowloss)
{
  int row = blockIdx.x, tid = threadIdx.x;
  const float* lr = logits + (size_t)row * NV;
  const float4* l4 = (const float4*)lr;
  float vals[32];
  float mx = -1e30f;
  #pragma unroll
  for (int p = 0; p < 8; ++p) {
    float4 t = l4[p * 256 + tid];
    vals[p*4+0] = t.x; vals[p*4+1] = t.y; vals[p*4+2] = t.z; vals[p*4+3] = t.w;
    mx = fmaxf(mx, fmaxf(fmaxf(t.x, t.y), fmaxf(t.z, t.w)));
  }
  #pragma unroll
  for (int d = 1; d < 64; d <<= 1) mx = fmaxf(mx, __shfl_xor(mx, d));
  __shared__ float red[4], red2[4];
  int w = tid >> 6, lane = tid & 63;
  if (lane == 0) red[w] = mx;
  __syncthreads();
  mx = fmaxf(fmaxf(red[0], red[1]), fmaxf(red[2], red[3]));
  float sm = 0.f;
  #pragma unroll
  for (int i = 0; i < 32; ++i) sm += __expf(vals[i] - mx);
  #pragma unroll
  for (int d = 1; d < 64; d <<= 1) sm += __shfl_xor(sm, d);
  if (lane == 0) red2[w] = sm;
  __syncthreads();
  if (tid == 0) {
    float total = red2[0] + red2[1] + red2[2] + red2[3];
    float lse = mx + __logf(total);
    rowloss[row] = lse - lr[targets[row]];
  }
}

__global__ __launch_bounds__(256) void loss_reduce(
    const float* __restrict__ rowloss, float* __restrict__ out_loss)
{
  int tid = threadIdx.x;
  float s = 0.f;
  #pragma unroll
  for (int i = 0; i < 32; ++i) s += rowloss[tid + i * 256];
  #pragma unroll
  for (int d = 1; d < 64; d <<= 1) s += __shfl_xor(s, d);
  __shared__ float red[4];
  int w = tid >> 6, lane = tid & 63;
  if (lane == 0) red[w] = s;
  __syncthreads();
  if (tid == 0) {
    float total = red[0] + red[1] + red[2] + red[3];
    out_loss[0] = total * (1.0f / NTOK);
  }
}

// ---------------- launch ----------------
extern "C" void kernel_launch(void* const* d_in, const int* in_sizes, int n_in,
                              void* d_out, int out_size, void* d_ws, size_t ws_size,
                              hipStream_t stream)
{
  const int*   idx     = (const int*)d_in[0];
  const int*   targets = (const int*)d_in[1];
  const float* tok     = (const float*)d_in[2];
  const float* pos     = (const float*)d_in[3];
  const float* ln1g    = (const float*)d_in[4];
  const float* ln1b    = (const float*)d_in[5];
  const float* Wq      = (const float*)d_in[6];
  const float* Wk      = (const float*)d_in[7];
  const float* Wv      = (const float*)d_in[8];
  const float* Wp      = (const float*)d_in[9];
  const float* bp      = (const float*)d_in[10];
  const float* ln2g    = (const float*)d_in[11];
  const float* ln2b    = (const float*)d_in[12];
  const float* W1      = (const float*)d_in[13];
  const float* b1      = (const float*)d_in[14];
  const float* W2      = (const float*)d_in[15];
  const float* b2      = (const float*)d_in[16];
  const float* lnfg    = (const float*)d_in[17];
  const float* lnfb    = (const float*)d_in[18];
  const float* Wlm     = (const float*)d_in[19];
  const float* blm     = (const float*)d_in[20];

  // d_out (f32, 268,435,460 B) doubles as scratch; everything in it is dead
  // before the final logits GEMM rewrites the full buffer.
  //   [0, 25.2 MB)        x residual f32 [NTOK][ND]
  //   [25.2, 75.5 MB)     qkv bf16 [NTOK][2304]  /  mid bf16 [NTOK][NFF] (union)
  //   [75.5, 160.5 MB)    all-layer transposed weights (bf16)
  char* ob = (char*)d_out;
  float*  x    = (float*)ob;
  ushort* qkvb = (ushort*)(ob + 25165824);
  ushort* mid  = (ushort*)(ob + 25165824);
  ushort* qkvT = (ushort*)(ob + 75497472);                  // 6 x [2304][768]
  ushort* wpT  = (ushort*)(ob + 75497472 + 21233664);       // 6 x [768][768]
  ushort* w1T  = (ushort*)(ob + 75497472 + 28311552);       // 6 x [3072][768]
  ushort* w2T  = (ushort*)(ob + 75497472 + 56623104);       // 6 x [768][3072]
  float* logits = (float*)d_out;

  char* ws = (char*)d_ws;
  size_t off = 0;
  auto alloc = [&](size_t bytes) -> void* {
    void* p = ws + off; off += (bytes + 255) & ~(size_t)255; return p;
  };
  ushort* h    = (ushort*)alloc((size_t)NTOK * ND * 2);     // ln out / attn out
  ushort* wlmT = (ushort*)alloc((size_t)ND * NV * 2);       // read during logits GEMM
  float*  rowloss = (float*)alloc((size_t)NTOK * 4);

  embed_kernel<<<NTOK, 192, 0, stream>>>(idx, tok, pos, x);

  // ---- all weight transposes up front (batched across layers) ----
  const size_t LQKV = (size_t)2304 * ND;   // per-layer qkvT stride (elements)
  {
    int tq = NL * NH * ND * NDH;           // 3,538,944
    transp2<<<(tq + 255) / 256, 256, 0, stream>>>(Wq, qkvT,                 ND, NDH, NH, (size_t)NDH * ND, LQKV, tq);
    transp2<<<(tq + 255) / 256, 256, 0, stream>>>(Wk, qkvT + (size_t)ND*ND, ND, NDH, NH, (size_t)NDH * ND, LQKV, tq);
    transp2<<<(tq + 255) / 256, 256, 0, stream>>>(Wv, qkvT + (size_t)2*ND*ND, ND, NDH, NH, (size_t)NDH * ND, LQKV, tq);
    int tp = NL * ND * ND;
    transp2<<<(tp + 255) / 256, 256, 0, stream>>>(Wp, wpT, ND, ND, 1, 0, (size_t)ND * ND, tp);
    int tf = NL * ND * NFF;
    transp2<<<(tf + 255) / 256, 256, 0, stream>>>(W1, w1T, ND, NFF, 1, 0, (size_t)ND * NFF, tf);
    transp2<<<(tf + 255) / 256, 256, 0, stream>>>(W2, w2T, NFF, ND, 1, 0, (size_t)ND * NFF, tf);
    int tl = ND * NV;
    transp2<<<(tl + 255) / 256, 256, 0, stream>>>(Wlm, wlmT, ND, NV, 1, 0, (size_t)ND * NV, tl);
  }

  dim3 gqkv(2304 / 128, NTOK / 128);
  dim3 g768(ND / 128, NTOK / 128);
  dim3 gff(NFF / 128, NTOK / 128);

  for (int l = 0; l < NL; ++l) {
    ln_kernel<<<NTOK, 256, 0, stream>>>(x, ln1g + l * ND, ln1b + l * ND, h);
    gemm_bt<false,false,false,1><<<gqkv, 256, 0, stream>>>(h, qkvT + l * LQKV, nullptr, nullptr, qkvb, NTOK, 2304, ND);
    attn_kernel<<<NB * NH * (NT / 64), 256, 0, stream>>>(qkvb, h);
    gemm_bt<true,false,true,0><<<g768, 256, 0, stream>>>(h, wpT + (size_t)l * ND * ND, bp + l * ND, x, nullptr, NTOK, ND, ND);
    ln_kernel<<<NTOK, 256, 0, stream>>>(x, ln2g + l * ND, ln2b + l * ND, h);
    gemm_bt<true,true,false,1><<<gff, 256, 0, stream>>>(h, w1T + (size_t)l * ND * NFF, b1 + (size_t)l * NFF, nullptr, mid, NTOK, NFF, ND);
    gemm_bt<true,false,true,0><<<g768, 256, 0, stream>>>(mid, w2T + (size_t)l * ND * NFF, b2 + l * ND, x, nullptr, NTOK, ND, NFF);
  }

  ln_kernel<<<NTOK, 256, 0, stream>>>(x, lnfg, lnfb, h);
  dim3 glm(NV / 128, NTOK / 128);
  gemm_bt<true,false,false,2><<<glm, 256, 0, stream>>>(h, wlmT, blm, nullptr, logits, NTOK, NV, ND);

  loss_row<<<NTOK, 256, 0, stream>>>(logits, targets, rowloss);
  loss_reduce<<<1, 256, 0, stream>>>(rowloss, logits + (size_t)NTOK * NV);
}